// Round 15
// baseline (98.385 us; speedup 1.0000x reference)
//
#include <hip/hip_runtime.h>
#include <stdint.h>
#include <math.h>

// PhysicsForwardModel: B=2, Nz=Nx=128, Ly=Lx=512.
// out[b,t,l] = (1/3) * sum_j Cy[j,l] * sum_k cos(F[k,j]*t) * a[k] * (Cy[:,:128] x[b] Cy[:,128:256]^T)[k,j]
//              + std_b * N(0,1)  (JAX threefry key=42, partitionable counters, XLA erfinv)
// R24: R23 + source-level software pipelining (bit-identical values, pure reorder):
//      - stageB phase C: load kq[k+1] + compute its 2 anchor cos BEFORE iteration k's
//        46-fma block (hides ds_read+trans latency under fma issue; R8->R9 precedent).
//      - stageC: compute next 16-j block's 2 anchor cos before current block's fmas.
//      R23's LDS-halving was neutral -> stages are dependent-chain latency-bound at
//      2 waves/SIMD, not LDS-pipe-bound. This attacks the serial chain head.

#define HALF_N 262144  // 512*512 per-batch elements
#define PI_F 3.14159274101257324f

// ws layout (floats): Vt [0..524288) [j][b][t]; partial [524288..526336) 512 x {s0,q0,s1,q1}

__device__ __forceinline__ uint32_t rotl32(uint32_t v, int r) {
  return (v << r) | (v >> (32 - r));
}

// XLA ErfInv32 (Giles) -- matches reference's lax.erf_inv
__device__ __forceinline__ float erfinv_xla(float x) {
  float w = -log1pf(__fmul_rn(-x, x));
  float p;
  if (w < 5.0f) {
    w = w - 2.5f;
    p = 2.81022636e-08f;
    p = fmaf(p, w, 3.43273939e-07f);
    p = fmaf(p, w, -3.5233877e-06f);
    p = fmaf(p, w, -4.39150654e-06f);
    p = fmaf(p, w, 0.00021858087f);
    p = fmaf(p, w, -0.00125372503f);
    p = fmaf(p, w, -0.00417768164f);
    p = fmaf(p, w, 0.246640727f);
    p = fmaf(p, w, 1.50140941f);
  } else {
    w = __fsqrt_rn(w) - 3.0f;
    p = -0.000200214257f;
    p = fmaf(p, w, 0.000100950558f);
    p = fmaf(p, w, 0.00134934322f);
    p = fmaf(p, w, -0.00367342844f);
    p = fmaf(p, w, 0.00573950773f);
    p = fmaf(p, w, -0.0076224613f);
    p = fmaf(p, w, 0.00943887047f);
    p = fmaf(p, w, 1.00167406f);
    p = fmaf(p, w, 2.83297682f);
  }
  return p * x;
}

// Cy[k,n] = sc(k) * 2 * cos(pi*(2n+1)*k/1024), with n2p1 = (float)(2n+1) exact
__device__ __forceinline__ float cy_elem(float n2p1, float kf, float sc) {
  float t1 = __fmul_rn(PI_F, n2p1);
  float arg = __fmul_rn(t1, kf) * (1.0f / 1024.0f);
  return __fmul_rn(sc, __fmul_rn(2.0f, __cosf(arg)));
}

// fusedB, block = j (grid 512, 512 threads):
//   A/A2/B byte-identical to R22; phase C software-pipelined (bit-identical values).
__global__ __launch_bounds__(512, 4) void stageB_kernel(const float* __restrict__ x,
                                                        float* __restrict__ Vt) {
  __shared__ float cyl[128];
  __shared__ float us[256];
  __shared__ float4 kq[512];
  __shared__ float red[16][512];
  int j = blockIdx.x;
  int tid = threadIdx.x;
  float jf = (float)j;
  if (tid < 128) {
    float scj = (j == 0) ? (1.0f / __fsqrt_rn(2048.0f)) : 0.03125f;
    cyl[tid] = cy_elem((float)(2 * (128 + tid) + 1), jf, scj);
  }
  __syncthreads();
  if (tid < 256) {
    int b = tid >> 7, i = tid & 127;
    const float* xr = x + (b * 128 + i) * 128;
    float accA = 0.0f, accB = 0.0f;
    for (int jj = 0; jj < 128; jj += 8) {
      float4 xa = *(const float4*)&xr[jj];
      float4 xb = *(const float4*)&xr[jj + 4];
      float4 ca = *(const float4*)&cyl[jj];
      float4 cb = *(const float4*)&cyl[jj + 4];
      accA = fmaf(xa.x, ca.x, accA); accB = fmaf(xa.y, ca.y, accB);
      accA = fmaf(xa.z, ca.z, accA); accB = fmaf(xa.w, ca.w, accB);
      accA = fmaf(xb.x, cb.x, accA); accB = fmaf(xb.y, cb.y, accB);
      accA = fmaf(xb.z, cb.z, accA); accB = fmaf(xb.w, cb.w, accB);
    }
    us[tid] = accA + accB;
  }
  __syncthreads();
  {
    float kf = (float)tid;
    float sc = (tid == 0) ? (1.0f / __fsqrt_rn(2048.0f)) : 0.03125f;
    // coefficient recurrence step: 2*cos(pi*k/512)  (PI_F/512 exact pow2 scale)
    float thc = __cosf(__fmul_rn(kf, PI_F / 512.0f));
    float k2b = thc + thc;  // exact *2
    float a = cy_elem(1.0f, kf, sc);   // i=0 anchor (bit-identical)
    float c1 = cy_elem(3.0f, kf, sc);  // i=1 anchor (bit-identical)
    float acc0 = __fmul_rn(a, us[0]);
    float acc1 = __fmul_rn(a, us[128]);
    float accA0 = 0.f, accA1 = 0.f;
    acc0 = fmaf(c1, us[1], acc0);   acc1 = fmaf(c1, us[129], acc1);
    float cc2 = fmaf(k2b, c1, -a);      // i=2 (recurred)
    accA0 = fmaf(cc2, us[2], accA0); accA1 = fmaf(cc2, us[130], accA1);
    float cc3 = fmaf(k2b, cc2, -c1);    // i=3
    acc0 = fmaf(cc3, us[3], acc0);   acc1 = fmaf(cc3, us[131], acc1);
    float cm2 = cc2, cm1 = cc3;
#pragma unroll
    for (int q = 1; q < 4; ++q) {  // i = 4..15
      int i = q << 2;
      float4 v0 = *(const float4*)&us[i];
      float4 v1 = *(const float4*)&us[128 + i];
      float d0 = fmaf(k2b, cm1, -cm2);
      acc0 = fmaf(d0, v0.x, acc0);   acc1 = fmaf(d0, v1.x, acc1);
      float d1 = fmaf(k2b, d0, -cm1);
      accA0 = fmaf(d1, v0.y, accA0); accA1 = fmaf(d1, v1.y, accA1);
      float d2 = fmaf(k2b, d1, -d0);
      acc0 = fmaf(d2, v0.z, acc0);   acc1 = fmaf(d2, v1.z, acc1);
      float d3 = fmaf(k2b, d2, -d1);
      accA0 = fmaf(d3, v0.w, accA0); accA1 = fmaf(d3, v1.w, accA1);
      cm2 = d2; cm1 = d3;
    }
    for (int i0 = 16; i0 < 128; i0 += 16) {
      float b0f = (float)(2 * i0 + 1);
      float ca = cy_elem(b0f, kf, sc);                   // anchor i0 (R1-exact expr)
      float cb = cy_elem(__fadd_rn(b0f, 2.0f), kf, sc);  // anchor i0+1 (R1-exact expr)
      float4 u0 = *(const float4*)&us[i0];
      float4 u1 = *(const float4*)&us[128 + i0];
      acc0 = fmaf(ca, u0.x, acc0);   acc1 = fmaf(ca, u1.x, acc1);
      accA0 = fmaf(cb, u0.y, accA0); accA1 = fmaf(cb, u1.y, accA1);
      float d2 = fmaf(k2b, cb, -ca);
      acc0 = fmaf(d2, u0.z, acc0);   acc1 = fmaf(d2, u1.z, acc1);
      float d3 = fmaf(k2b, d2, -cb);
      accA0 = fmaf(d3, u0.w, accA0); accA1 = fmaf(d3, u1.w, accA1);
      cm2 = d2; cm1 = d3;
#pragma unroll
      for (int q = 1; q < 4; ++q) {
        int i = i0 + (q << 2);
        float4 v0 = *(const float4*)&us[i];
        float4 v1 = *(const float4*)&us[128 + i];
        float d0 = fmaf(k2b, cm1, -cm2);
        acc0 = fmaf(d0, v0.x, acc0);   acc1 = fmaf(d0, v1.x, acc1);
        float d1 = fmaf(k2b, d0, -cm1);
        accA0 = fmaf(d1, v0.y, accA0); accA1 = fmaf(d1, v1.y, accA1);
        float e2 = fmaf(k2b, d1, -d0);
        acc0 = fmaf(e2, v0.z, acc0);   acc1 = fmaf(e2, v1.z, acc1);
        float e3 = fmaf(k2b, e2, -d1);
        accA0 = fmaf(e3, v0.w, accA0); accA1 = fmaf(e3, v1.w, accA1);
        cm2 = e2; cm1 = e3;
      }
    }
    acc0 += accA0;
    acc1 += accA1;
    const float w0 = PI_F / 512.0f;  // exact pow2 scale of pi_f
    float ky = __fmul_rn(kf, w0);
    float kx = __fmul_rn(jf, w0);
    float fsv = __fsqrt_rn(__fadd_rn(__fmul_rn(ky, ky), __fmul_rn(kx, kx)));
    float cs = __cosf(__fmul_rn(fsv, 32.0f));  // t-step cosine, hoisted
    kq[tid] = make_float4(fsv, __fmul_rn(a, acc0), __fmul_rn(a, acc1), cs);
  }
  __syncthreads();
  // Phase C (pipelined): thread (kg, tg); t = tg + 32n (n=0..15); k in [32kg, 32kg+32)
  int kg = tid >> 5, tg = tid & 31;
  int kbeg = kg << 5;
  float tfa = (float)tg;         // anchor t
  float tfb = (float)(tg + 32);  // anchor t + 32
  float a0[16], a1[16];
#pragma unroll
  for (int n = 0; n < 16; ++n) { a0[n] = 0.0f; a1[n] = 0.0f; }
  // prologue: load k=kbeg and its anchors
  float4 q = kq[kbeg];
  float ca = __cosf(__fmul_rn(q.x, tfa));  // bit-matches ref at t = tg
  float cb = __cosf(__fmul_rn(q.x, tfb));  // bit-matches ref at t = tg+32
  for (int kk = 0; kk < 32; ++kk) {
    float m0 = q.y, m1 = q.z;
    float k2 = q.w + q.w;  // 2*cos(32F), exact *2
    float xa = ca, xb = cb;
    if (kk < 31) {  // issue next k's load + anchors before this k's fma block
      float4 qn = kq[kbeg + kk + 1];
      ca = __cosf(__fmul_rn(qn.x, tfa));
      cb = __cosf(__fmul_rn(qn.x, tfb));
      q = qn;
    }
    a0[0] = fmaf(xa, m0, a0[0]); a1[0] = fmaf(xa, m1, a1[0]);
    a0[1] = fmaf(xb, m0, a0[1]); a1[1] = fmaf(xb, m1, a1[1]);
#pragma unroll
    for (int n = 2; n < 16; ++n) {
      float cn = fmaf(k2, xb, -xa);
      a0[n] = fmaf(cn, m0, a0[n]); a1[n] = fmaf(cn, m1, a1[n]);
      xa = xb; xb = cn;
    }
  }
  // reduce b0 then b1 across kg (ascending, fixed order); red[kg][t] 2-way (free)
#pragma unroll
  for (int n = 0; n < 16; ++n) red[kg][(n << 5) + tg] = a0[n];
  __syncthreads();
  float s0 = red[0][tid];
#pragma unroll
  for (int g = 1; g < 16; ++g) s0 += red[g][tid];
  __syncthreads();
#pragma unroll
  for (int n = 0; n < 16; ++n) red[kg][(n << 5) + tg] = a1[n];
  __syncthreads();
  float s1 = red[0][tid];
#pragma unroll
  for (int g = 1; g < 16; ++g) s1 += red[g][tid];
  Vt[(j << 10) + tid] = s0;
  Vt[(j << 10) + 512 + tid] = s1;
}

// stageC v7: parity-symmetric + b128 pairs + pipelined anchors. block = t (grid 512, 256 thr).
// Same coefficient values and fma order as R22/R23 -> bit-identical out.
__global__ __launch_bounds__(256, 4) void stageC_kernel(const float* __restrict__ Vt,
                                                        float* __restrict__ out,
                                                        float* __restrict__ partial) {
  __shared__ float vq[1024];  // [j][2] = {b0, b1} for this block's t
  int t = blockIdx.x;
  int tid = threadIdx.x;
  {
    const float* b0p = Vt + (tid << 10);
    const float* b1p = b0p + 512;
    vq[2 * tid] = b0p[t];
    vq[2 * tid + 1] = b1p[t];
    const float* b0q = Vt + ((tid + 256) << 10);
    const float* b1q = b0q + 512;
    vq[2 * tid + 512] = b0q[t];
    vq[2 * tid + 513] = b1q[t];
  }
  __syncthreads();
  int l = tid;
  float t1 = __fmul_rn(PI_F, (float)(2 * l + 1));
  float cth = __cosf(__fmul_rn(t1, 1.0f) * (1.0f / 1024.0f));
  float k2 = cth + cth;  // exact *2
  float cy0 = __fmul_rn(1.0f / __fsqrt_rn(2048.0f), 2.0f);
  float c16 = __fmul_rn(cy0, 16.0f);
  float e0, e1, o0, o1;
  float c_m1, c_m2;
  {
    // pair (0,1): b128 = {j0.b0, j0.b1, j1.b0, j1.b1}
    float4 v01 = *(const float4*)&vq[0];
    e0 = __fmul_rn(c16, v01.x);
    e1 = __fmul_rn(c16, v01.y);
    o0 = __fmul_rn(cth, v01.z);
    o1 = __fmul_rn(cth, v01.w);
    float c2v = __cosf(__fmul_rn(t1, 2.0f) * (1.0f / 1024.0f));
    // pair (2,3): c2 anchor, c3 recurred
    float4 v23 = *(const float4*)&vq[4];
    e0 = fmaf(c2v, v23.x, e0); e1 = fmaf(c2v, v23.y, e1);
    float c3 = fmaf(k2, c2v, -cth);
    o0 = fmaf(c3, v23.z, o0); o1 = fmaf(c3, v23.w, o1);
    c_m2 = c2v; c_m1 = c3;
#pragma unroll
    for (int j = 4; j < 16; j += 2) {
      float4 v = *(const float4*)&vq[j << 1];
      float cj = fmaf(k2, c_m1, -c_m2);
      e0 = fmaf(cj, v.x, e0); e1 = fmaf(cj, v.y, e1);
      float cj1 = fmaf(k2, cj, -c_m1);
      o0 = fmaf(cj1, v.z, o0); o1 = fmaf(cj1, v.w, o1);
      c_m2 = cj; c_m1 = cj1;
    }
  }
  // pipelined anchors: compute block j0's anchors one iteration ahead
  float nca, ncb;
  {
    float jb = (float)16;
    nca = __cosf(__fmul_rn(t1, jb) * (1.0f / 1024.0f));
    ncb = __cosf(__fmul_rn(t1, __fadd_rn(jb, 1.0f)) * (1.0f / 1024.0f));
  }
  for (int j0 = 16; j0 < 512; j0 += 16) {
    float ca = nca, cb = ncb;
    int jn = j0 + 16;
    if (jn < 512) {  // issue next block's anchor cos before this block's fmas
      float jb = (float)jn;
      nca = __cosf(__fmul_rn(t1, jb) * (1.0f / 1024.0f));
      ncb = __cosf(__fmul_rn(t1, __fadd_rn(jb, 1.0f)) * (1.0f / 1024.0f));
    }
    float4 vab = *(const float4*)&vq[j0 << 1];
    e0 = fmaf(ca, vab.x, e0); e1 = fmaf(ca, vab.y, e1);
    o0 = fmaf(cb, vab.z, o0); o1 = fmaf(cb, vab.w, o1);
    c_m2 = ca; c_m1 = cb;
#pragma unroll
    for (int n = 2; n < 16; n += 2) {
      float4 v = *(const float4*)&vq[(j0 + n) << 1];
      float cj = fmaf(k2, c_m1, -c_m2);
      e0 = fmaf(cj, v.x, e0); e1 = fmaf(cj, v.y, e1);
      float cj1 = fmaf(k2, cj, -c_m1);
      o0 = fmaf(cj1, v.z, o0); o1 = fmaf(cj1, v.w, o1);
      c_m2 = cj; c_m1 = cj1;
    }
  }
  float pA0 = __fmul_rn(e0 + o0, 0.0625f) / 3.0f;  // (t, l, b0)
  float pA1 = __fmul_rn(e1 + o1, 0.0625f) / 3.0f;  // (t, l, b1)
  float pB0 = __fmul_rn(e0 - o0, 0.0625f) / 3.0f;  // (t, 511-l, b0)
  float pB1 = __fmul_rn(e1 - o1, 0.0625f) / 3.0f;  // (t, 511-l, b1)
  int lr = 511 - l;
  out[(t << 9) + l] = pA0;
  out[HALF_N + (t << 9) + l] = pA1;
  out[(t << 9) + lr] = pB0;
  out[HALF_N + (t << 9) + lr] = pB1;
  float s0 = pA0 + pB0, q0 = fmaf(pA0, pA0, pB0 * pB0);
  float s1 = pA1 + pB1, q1 = fmaf(pA1, pA1, pB1 * pB1);
  for (int off = 32; off > 0; off >>= 1) {
    s0 += __shfl_down(s0, off);
    q0 += __shfl_down(q0, off);
    s1 += __shfl_down(s1, off);
    q1 += __shfl_down(q1, off);
  }
  __shared__ float red[4][4];
  int wave = tid >> 6;
  if ((tid & 63) == 0) {
    red[wave][0] = s0; red[wave][1] = q0; red[wave][2] = s1; red[wave][3] = q1;
  }
  __syncthreads();
  if (tid == 0) {
    float a0 = 0.f, a1 = 0.f, a2 = 0.f, a3 = 0.f;
    for (int wv = 0; wv < 4; ++wv) {
      a0 += red[wv][0]; a1 += red[wv][1]; a2 += red[wv][2]; a3 += red[wv][3];
    }
    partial[blockIdx.x * 4 + 0] = a0;
    partial[blockIdx.x * 4 + 1] = a1;
    partial[blockIdx.x * 4 + 2] = a2;
    partial[blockIdx.x * 4 + 3] = a3;
  }
}

// Fused stats + noise: redundant partial reduce (512 quads) -> (std0,std1), then threefry noise.
// element i -> threefry2x32(key=(0,42), ctr=(0,i)), bits = o0^o1
__global__ __launch_bounds__(256) void noise_kernel(float* __restrict__ out,
                                                    const float* __restrict__ partial) {
  int tid = threadIdx.x;
  const float4* pq = (const float4*)partial;  // 512 quads {s0,q0,s1,q1}
  float4 pa = pq[tid];
  float4 pb = pq[tid + 256];
  float s0 = pa.x + pb.x, q0 = pa.y + pb.y, s1 = pa.z + pb.z, q1 = pa.w + pb.w;
  for (int off = 32; off > 0; off >>= 1) {
    s0 += __shfl_down(s0, off);
    q0 += __shfl_down(q0, off);
    s1 += __shfl_down(s1, off);
    q1 += __shfl_down(q1, off);
  }
  __shared__ float red[4][4];
  int wave = tid >> 6;
  if ((tid & 63) == 0) {
    red[wave][0] = s0; red[wave][1] = q0; red[wave][2] = s1; red[wave][3] = q1;
  }
  __syncthreads();
  float S = red[0][0] + red[1][0] + red[2][0] + red[3][0];
  float Q = red[0][1] + red[1][1] + red[2][1] + red[3][1];
  float S2 = red[0][2] + red[1][2] + red[2][2] + red[3][2];
  float Q2 = red[0][3] + red[1][3] + red[2][3] + red[3][3];
  const float invN = 1.0f / 262144.0f;
  float m0 = S * invN, m1 = S2 * invN;
  float std0 = __fsqrt_rn(fmaxf(Q * invN - m0 * m0, 0.0f));
  float std1 = __fsqrt_rn(fmaxf(Q2 * invN - m1 * m1, 0.0f));

  int i = blockIdx.x * 256 + tid;  // < 524288
  uint32_t x0 = 0u;
  uint32_t x1 = (uint32_t)i;
  const uint32_t k0 = 0u, k1 = 42u;
  const uint32_t k2 = k0 ^ k1 ^ 0x1BD11BDAu;
  x0 += k0; x1 += k1;
#define QR(r) x0 += x1; x1 = rotl32(x1, r); x1 ^= x0;
  QR(13) QR(15) QR(26) QR(6)
  x0 += k1; x1 += k2 + 1u;
  QR(17) QR(29) QR(16) QR(24)
  x0 += k2; x1 += k0 + 2u;
  QR(13) QR(15) QR(26) QR(6)
  x0 += k0; x1 += k1 + 3u;
  QR(17) QR(29) QR(16) QR(24)
  x0 += k1; x1 += k2 + 4u;
  QR(13) QR(15) QR(26) QR(6)
  x0 += k2; x1 += k0 + 5u;
#undef QR
  uint32_t bits = x0 ^ x1;
  const float lo = __uint_as_float(0xBF7FFFFFu);  // nextafter(-1,0)
  float f = __uint_as_float((bits >> 9) | 0x3F800000u) - 1.0f;
  float u = fmaxf(lo, __fadd_rn(__fmul_rn(f, 2.0f), lo));
  const float sqrt2 = 1.41421356237309515f;
  out[i] += (i < HALF_N ? std0 : std1) * (sqrt2 * erfinv_xla(u));
}

extern "C" void kernel_launch(void* const* d_in, const int* in_sizes, int n_in,
                              void* d_out, int out_size, void* d_ws, size_t ws_size,
                              hipStream_t stream) {
  const float* x = (const float*)d_in[0];
  float* ws = (float*)d_ws;
  float* Vt      = ws;
  float* partial = ws + 524288;
  float* out = (float*)d_out;

  stageB_kernel<<<512, 512, 0, stream>>>(x, Vt);
  stageC_kernel<<<512, 256, 0, stream>>>(Vt, out, partial);
  noise_kernel<<<2048, 256, 0, stream>>>(out, partial);
}

// Round 16
// 98.183 us; speedup vs baseline: 1.0021x; 1.0021x over previous
//
#include <hip/hip_runtime.h>
#include <stdint.h>
#include <math.h>

// PhysicsForwardModel: B=2, Nz=Nx=128, Ly=Lx=512.
// out[b,t,l] = (1/3) * sum_j Cy[j,l] * sum_k cos(F[k,j]*t) * a[k] * (Cy[:,:128] x[b] Cy[:,128:256]^T)[k,j]
//              + std_b * N(0,1)  (JAX threefry key=42, partitionable counters, XLA erfinv)
// R25: stageB = R23/R22 byte-for-byte (R24 pipelining was neutral -> reverted). stageC v8:
//      intra-block j-split -- 512 threads, thread (jh=tid>>8, l=tid&255) computes partial
//      (E,O) over j-half [256*jh, 256*jh+256) (same anchors/recurrence), LDS-combine
//      E=E_lo+E_hi / O=O_lo+O_hi, then R21 parity tail. Per-thread work halves, occupancy
//      8 -> 16 waves/CU, data movement unchanged. E/O regroup at j=256: ulp-class (R18
//      j-quarter split precedent). Attacks stageC's unexplained 23us (issue model ~5us)
//      via TLP, the one axis not yet isolated cleanly (R16 confounded it with 2x cos).

#define HALF_N 262144  // 512*512 per-batch elements
#define PI_F 3.14159274101257324f

// ws layout (floats): Vt [0..524288) [j][b][t]; partial [524288..526336) 512 x {s0,q0,s1,q1}

__device__ __forceinline__ uint32_t rotl32(uint32_t v, int r) {
  return (v << r) | (v >> (32 - r));
}

// XLA ErfInv32 (Giles) -- matches reference's lax.erf_inv
__device__ __forceinline__ float erfinv_xla(float x) {
  float w = -log1pf(__fmul_rn(-x, x));
  float p;
  if (w < 5.0f) {
    w = w - 2.5f;
    p = 2.81022636e-08f;
    p = fmaf(p, w, 3.43273939e-07f);
    p = fmaf(p, w, -3.5233877e-06f);
    p = fmaf(p, w, -4.39150654e-06f);
    p = fmaf(p, w, 0.00021858087f);
    p = fmaf(p, w, -0.00125372503f);
    p = fmaf(p, w, -0.00417768164f);
    p = fmaf(p, w, 0.246640727f);
    p = fmaf(p, w, 1.50140941f);
  } else {
    w = __fsqrt_rn(w) - 3.0f;
    p = -0.000200214257f;
    p = fmaf(p, w, 0.000100950558f);
    p = fmaf(p, w, 0.00134934322f);
    p = fmaf(p, w, -0.00367342844f);
    p = fmaf(p, w, 0.00573950773f);
    p = fmaf(p, w, -0.0076224613f);
    p = fmaf(p, w, 0.00943887047f);
    p = fmaf(p, w, 1.00167406f);
    p = fmaf(p, w, 2.83297682f);
  }
  return p * x;
}

// Cy[k,n] = sc(k) * 2 * cos(pi*(2n+1)*k/1024), with n2p1 = (float)(2n+1) exact
__device__ __forceinline__ float cy_elem(float n2p1, float kf, float sc) {
  float t1 = __fmul_rn(PI_F, n2p1);
  float arg = __fmul_rn(t1, kf) * (1.0f / 1024.0f);
  return __fmul_rn(sc, __fmul_rn(2.0f, __cosf(arg)));
}

// fusedB, block = j (grid 512, 512 threads):  [R22/R23-verified, byte-identical]
__global__ __launch_bounds__(512, 4) void stageB_kernel(const float* __restrict__ x,
                                                        float* __restrict__ Vt) {
  __shared__ float cyl[128];
  __shared__ float us[256];
  __shared__ float4 kq[512];
  __shared__ float red[16][512];
  int j = blockIdx.x;
  int tid = threadIdx.x;
  float jf = (float)j;
  if (tid < 128) {
    float scj = (j == 0) ? (1.0f / __fsqrt_rn(2048.0f)) : 0.03125f;
    cyl[tid] = cy_elem((float)(2 * (128 + tid) + 1), jf, scj);
  }
  __syncthreads();
  if (tid < 256) {
    int b = tid >> 7, i = tid & 127;
    const float* xr = x + (b * 128 + i) * 128;
    float accA = 0.0f, accB = 0.0f;
    for (int jj = 0; jj < 128; jj += 8) {
      float4 xa = *(const float4*)&xr[jj];
      float4 xb = *(const float4*)&xr[jj + 4];
      float4 ca = *(const float4*)&cyl[jj];
      float4 cb = *(const float4*)&cyl[jj + 4];
      accA = fmaf(xa.x, ca.x, accA); accB = fmaf(xa.y, ca.y, accB);
      accA = fmaf(xa.z, ca.z, accA); accB = fmaf(xa.w, ca.w, accB);
      accA = fmaf(xb.x, cb.x, accA); accB = fmaf(xb.y, cb.y, accB);
      accA = fmaf(xb.z, cb.z, accA); accB = fmaf(xb.w, cb.w, accB);
    }
    us[tid] = accA + accB;
  }
  __syncthreads();
  {
    float kf = (float)tid;
    float sc = (tid == 0) ? (1.0f / __fsqrt_rn(2048.0f)) : 0.03125f;
    // coefficient recurrence step: 2*cos(pi*k/512)  (PI_F/512 exact pow2 scale)
    float thc = __cosf(__fmul_rn(kf, PI_F / 512.0f));
    float k2b = thc + thc;  // exact *2
    float a = cy_elem(1.0f, kf, sc);   // i=0 anchor (bit-identical)
    float c1 = cy_elem(3.0f, kf, sc);  // i=1 anchor (bit-identical)
    float acc0 = __fmul_rn(a, us[0]);
    float acc1 = __fmul_rn(a, us[128]);
    float accA0 = 0.f, accA1 = 0.f;
    acc0 = fmaf(c1, us[1], acc0);   acc1 = fmaf(c1, us[129], acc1);
    float cc2 = fmaf(k2b, c1, -a);      // i=2 (recurred)
    accA0 = fmaf(cc2, us[2], accA0); accA1 = fmaf(cc2, us[130], accA1);
    float cc3 = fmaf(k2b, cc2, -c1);    // i=3
    acc0 = fmaf(cc3, us[3], acc0);   acc1 = fmaf(cc3, us[131], acc1);
    float cm2 = cc2, cm1 = cc3;
#pragma unroll
    for (int q = 1; q < 4; ++q) {  // i = 4..15
      int i = q << 2;
      float4 v0 = *(const float4*)&us[i];
      float4 v1 = *(const float4*)&us[128 + i];
      float d0 = fmaf(k2b, cm1, -cm2);
      acc0 = fmaf(d0, v0.x, acc0);   acc1 = fmaf(d0, v1.x, acc1);
      float d1 = fmaf(k2b, d0, -cm1);
      accA0 = fmaf(d1, v0.y, accA0); accA1 = fmaf(d1, v1.y, accA1);
      float d2 = fmaf(k2b, d1, -d0);
      acc0 = fmaf(d2, v0.z, acc0);   acc1 = fmaf(d2, v1.z, acc1);
      float d3 = fmaf(k2b, d2, -d1);
      accA0 = fmaf(d3, v0.w, accA0); accA1 = fmaf(d3, v1.w, accA1);
      cm2 = d2; cm1 = d3;
    }
    for (int i0 = 16; i0 < 128; i0 += 16) {
      float b0f = (float)(2 * i0 + 1);
      float ca = cy_elem(b0f, kf, sc);                   // anchor i0 (R1-exact expr)
      float cb = cy_elem(__fadd_rn(b0f, 2.0f), kf, sc);  // anchor i0+1 (R1-exact expr)
      float4 u0 = *(const float4*)&us[i0];
      float4 u1 = *(const float4*)&us[128 + i0];
      acc0 = fmaf(ca, u0.x, acc0);   acc1 = fmaf(ca, u1.x, acc1);
      accA0 = fmaf(cb, u0.y, accA0); accA1 = fmaf(cb, u1.y, accA1);
      float d2 = fmaf(k2b, cb, -ca);
      acc0 = fmaf(d2, u0.z, acc0);   acc1 = fmaf(d2, u1.z, acc1);
      float d3 = fmaf(k2b, d2, -cb);
      accA0 = fmaf(d3, u0.w, accA0); accA1 = fmaf(d3, u1.w, accA1);
      cm2 = d2; cm1 = d3;
#pragma unroll
      for (int q = 1; q < 4; ++q) {
        int i = i0 + (q << 2);
        float4 v0 = *(const float4*)&us[i];
        float4 v1 = *(const float4*)&us[128 + i];
        float d0 = fmaf(k2b, cm1, -cm2);
        acc0 = fmaf(d0, v0.x, acc0);   acc1 = fmaf(d0, v1.x, acc1);
        float d1 = fmaf(k2b, d0, -cm1);
        accA0 = fmaf(d1, v0.y, accA0); accA1 = fmaf(d1, v1.y, accA1);
        float e2 = fmaf(k2b, d1, -d0);
        acc0 = fmaf(e2, v0.z, acc0);   acc1 = fmaf(e2, v1.z, acc1);
        float e3 = fmaf(k2b, e2, -d1);
        accA0 = fmaf(e3, v0.w, accA0); accA1 = fmaf(e3, v1.w, accA1);
        cm2 = e2; cm1 = e3;
      }
    }
    acc0 += accA0;
    acc1 += accA1;
    const float w0 = PI_F / 512.0f;  // exact pow2 scale of pi_f
    float ky = __fmul_rn(kf, w0);
    float kx = __fmul_rn(jf, w0);
    float fsv = __fsqrt_rn(__fadd_rn(__fmul_rn(ky, ky), __fmul_rn(kx, kx)));
    float cs = __cosf(__fmul_rn(fsv, 32.0f));  // t-step cosine, hoisted
    kq[tid] = make_float4(fsv, __fmul_rn(a, acc0), __fmul_rn(a, acc1), cs);
  }
  __syncthreads();
  // Phase C: thread (kg, tg); t = tg + 32n (n=0..15); k in [32kg, 32kg+32)
  int kg = tid >> 5, tg = tid & 31;
  int kbeg = kg << 5;
  float tfa = (float)tg;         // anchor t
  float tfb = (float)(tg + 32);  // anchor t + 32
  float a0[16], a1[16];
#pragma unroll
  for (int n = 0; n < 16; ++n) { a0[n] = 0.0f; a1[n] = 0.0f; }
  for (int kk = 0; kk < 32; ++kk) {
    float4 q = kq[kbeg + kk];
    float F = q.x, m0 = q.y, m1 = q.z;
    float k2 = q.w + q.w;  // 2*cos(32F), exact *2
    float ca = __cosf(__fmul_rn(F, tfa));  // bit-matches ref at t = tg
    float cb = __cosf(__fmul_rn(F, tfb));  // bit-matches ref at t = tg+32
    a0[0] = fmaf(ca, m0, a0[0]); a1[0] = fmaf(ca, m1, a1[0]);
    a0[1] = fmaf(cb, m0, a0[1]); a1[1] = fmaf(cb, m1, a1[1]);
#pragma unroll
    for (int n = 2; n < 16; ++n) {
      float cn = fmaf(k2, cb, -ca);
      a0[n] = fmaf(cn, m0, a0[n]); a1[n] = fmaf(cn, m1, a1[n]);
      ca = cb; cb = cn;
    }
  }
  // reduce b0 then b1 across kg (ascending, fixed order); red[kg][t] 2-way (free)
#pragma unroll
  for (int n = 0; n < 16; ++n) red[kg][(n << 5) + tg] = a0[n];
  __syncthreads();
  float s0 = red[0][tid];
#pragma unroll
  for (int g = 1; g < 16; ++g) s0 += red[g][tid];
  __syncthreads();
#pragma unroll
  for (int n = 0; n < 16; ++n) red[kg][(n << 5) + tg] = a1[n];
  __syncthreads();
  float s1 = red[0][tid];
#pragma unroll
  for (int g = 1; g < 16; ++g) s1 += red[g][tid];
  Vt[(j << 10) + tid] = s0;
  Vt[(j << 10) + 512 + tid] = s1;
}

// stageC v8: parity-symmetric + b128 pairs + intra-block j-split. block = t (grid 512,
// 512 threads, 16 waves/CU). Thread (jh=tid>>8, l=tid&255) accumulates (E,O) over its
// j-half; combine E=E_lo+E_hi (single regroup, ulp-class), then R21 parity tail.
__global__ __launch_bounds__(512, 4) void stageC_kernel(const float* __restrict__ Vt,
                                                        float* __restrict__ out,
                                                        float* __restrict__ partial) {
  __shared__ float vq[1024];      // [j][2] = {b0, b1} for this block's t
  __shared__ float comb[512][4];  // per-thread {e0,e1,o0,o1}
  __shared__ float redw[8][4];
  int t = blockIdx.x;
  int tid = threadIdx.x;
  vq[2 * tid] = Vt[(tid << 10) + t];
  vq[2 * tid + 1] = Vt[(tid << 10) + 512 + t];
  __syncthreads();
  int l = tid & 255;
  int jh = tid >> 8;
  float t1 = __fmul_rn(PI_F, (float)(2 * l + 1));
  float cth = __cosf(__fmul_rn(t1, 1.0f) * (1.0f / 1024.0f));
  float k2 = cth + cth;  // exact *2
  float e0, e1, o0, o1;
  float c_m1, c_m2;
  if (jh == 0) {
    float cy0 = __fmul_rn(1.0f / __fsqrt_rn(2048.0f), 2.0f);
    float c16 = __fmul_rn(cy0, 16.0f);
    // pair (0,1): b128 = {j0.b0, j0.b1, j1.b0, j1.b1}
    float4 v01 = *(const float4*)&vq[0];
    e0 = __fmul_rn(c16, v01.x);
    e1 = __fmul_rn(c16, v01.y);
    o0 = __fmul_rn(cth, v01.z);
    o1 = __fmul_rn(cth, v01.w);
    float c2v = __cosf(__fmul_rn(t1, 2.0f) * (1.0f / 1024.0f));
    float4 v23 = *(const float4*)&vq[4];
    e0 = fmaf(c2v, v23.x, e0); e1 = fmaf(c2v, v23.y, e1);
    float c3 = fmaf(k2, c2v, -cth);
    o0 = fmaf(c3, v23.z, o0); o1 = fmaf(c3, v23.w, o1);
    c_m2 = c2v; c_m1 = c3;
#pragma unroll
    for (int j = 4; j < 16; j += 2) {
      float4 v = *(const float4*)&vq[j << 1];
      float cj = fmaf(k2, c_m1, -c_m2);
      e0 = fmaf(cj, v.x, e0); e1 = fmaf(cj, v.y, e1);
      float cj1 = fmaf(k2, cj, -c_m1);
      o0 = fmaf(cj1, v.z, o0); o1 = fmaf(cj1, v.w, o1);
      c_m2 = cj; c_m1 = cj1;
    }
  } else {
    e0 = e1 = o0 = o1 = 0.0f;
  }
  int jbeg = (jh == 0) ? 16 : 256;
  int jend = jbeg + ((jh == 0) ? 240 : 256);
  for (int j0 = jbeg; j0 < jend; j0 += 16) {
    float jb = (float)j0;
    float ca = __cosf(__fmul_rn(t1, jb) * (1.0f / 1024.0f));                      // even
    float cb = __cosf(__fmul_rn(t1, __fadd_rn(jb, 1.0f)) * (1.0f / 1024.0f));    // odd
    float4 vab = *(const float4*)&vq[j0 << 1];
    e0 = fmaf(ca, vab.x, e0); e1 = fmaf(ca, vab.y, e1);
    o0 = fmaf(cb, vab.z, o0); o1 = fmaf(cb, vab.w, o1);
    c_m2 = ca; c_m1 = cb;
#pragma unroll
    for (int n = 2; n < 16; n += 2) {
      float4 v = *(const float4*)&vq[(j0 + n) << 1];
      float cj = fmaf(k2, c_m1, -c_m2);
      e0 = fmaf(cj, v.x, e0); e1 = fmaf(cj, v.y, e1);
      float cj1 = fmaf(k2, cj, -c_m1);
      o0 = fmaf(cj1, v.z, o0); o1 = fmaf(cj1, v.w, o1);
      c_m2 = cj; c_m1 = cj1;
    }
  }
  comb[tid][0] = e0; comb[tid][1] = e1; comb[tid][2] = o0; comb[tid][3] = o1;
  __syncthreads();
  float s0 = 0.f, q0 = 0.f, s1 = 0.f, q1 = 0.f;
  if (jh == 0) {
    float E0 = e0 + comb[tid + 256][0];
    float E1 = e1 + comb[tid + 256][1];
    float O0 = o0 + comb[tid + 256][2];
    float O1 = o1 + comb[tid + 256][3];
    float pA0 = __fmul_rn(E0 + O0, 0.0625f) / 3.0f;  // (t, l, b0)
    float pA1 = __fmul_rn(E1 + O1, 0.0625f) / 3.0f;  // (t, l, b1)
    float pB0 = __fmul_rn(E0 - O0, 0.0625f) / 3.0f;  // (t, 511-l, b0)
    float pB1 = __fmul_rn(E1 - O1, 0.0625f) / 3.0f;  // (t, 511-l, b1)
    int lr = 511 - l;
    out[(t << 9) + l] = pA0;
    out[HALF_N + (t << 9) + l] = pA1;
    out[(t << 9) + lr] = pB0;
    out[HALF_N + (t << 9) + lr] = pB1;
    s0 = pA0 + pB0; q0 = fmaf(pA0, pA0, pB0 * pB0);
    s1 = pA1 + pB1; q1 = fmaf(pA1, pA1, pB1 * pB1);
  }
  for (int off = 32; off > 0; off >>= 1) {
    s0 += __shfl_down(s0, off);
    q0 += __shfl_down(q0, off);
    s1 += __shfl_down(s1, off);
    q1 += __shfl_down(q1, off);
  }
  int wave = tid >> 6;
  if ((tid & 63) == 0) {
    redw[wave][0] = s0; redw[wave][1] = q0; redw[wave][2] = s1; redw[wave][3] = q1;
  }
  __syncthreads();
  if (tid == 0) {
    float a0 = 0.f, a1 = 0.f, a2 = 0.f, a3 = 0.f;
    for (int wv = 0; wv < 8; ++wv) {
      a0 += redw[wv][0]; a1 += redw[wv][1]; a2 += redw[wv][2]; a3 += redw[wv][3];
    }
    partial[blockIdx.x * 4 + 0] = a0;
    partial[blockIdx.x * 4 + 1] = a1;
    partial[blockIdx.x * 4 + 2] = a2;
    partial[blockIdx.x * 4 + 3] = a3;
  }
}

// Fused stats + noise: redundant partial reduce (512 quads) -> (std0,std1), then threefry noise.
// element i -> threefry2x32(key=(0,42), ctr=(0,i)), bits = o0^o1
__global__ __launch_bounds__(256) void noise_kernel(float* __restrict__ out,
                                                    const float* __restrict__ partial) {
  int tid = threadIdx.x;
  const float4* pq = (const float4*)partial;  // 512 quads {s0,q0,s1,q1}
  float4 pa = pq[tid];
  float4 pb = pq[tid + 256];
  float s0 = pa.x + pb.x, q0 = pa.y + pb.y, s1 = pa.z + pb.z, q1 = pa.w + pb.w;
  for (int off = 32; off > 0; off >>= 1) {
    s0 += __shfl_down(s0, off);
    q0 += __shfl_down(q0, off);
    s1 += __shfl_down(s1, off);
    q1 += __shfl_down(q1, off);
  }
  __shared__ float red[4][4];
  int wave = tid >> 6;
  if ((tid & 63) == 0) {
    red[wave][0] = s0; red[wave][1] = q0; red[wave][2] = s1; red[wave][3] = q1;
  }
  __syncthreads();
  float S = red[0][0] + red[1][0] + red[2][0] + red[3][0];
  float Q = red[0][1] + red[1][1] + red[2][1] + red[3][1];
  float S2 = red[0][2] + red[1][2] + red[2][2] + red[3][2];
  float Q2 = red[0][3] + red[1][3] + red[2][3] + red[3][3];
  const float invN = 1.0f / 262144.0f;
  float m0 = S * invN, m1 = S2 * invN;
  float std0 = __fsqrt_rn(fmaxf(Q * invN - m0 * m0, 0.0f));
  float std1 = __fsqrt_rn(fmaxf(Q2 * invN - m1 * m1, 0.0f));

  int i = blockIdx.x * 256 + tid;  // < 524288
  uint32_t x0 = 0u;
  uint32_t x1 = (uint32_t)i;
  const uint32_t k0 = 0u, k1 = 42u;
  const uint32_t k2 = k0 ^ k1 ^ 0x1BD11BDAu;
  x0 += k0; x1 += k1;
#define QR(r) x0 += x1; x1 = rotl32(x1, r); x1 ^= x0;
  QR(13) QR(15) QR(26) QR(6)
  x0 += k1; x1 += k2 + 1u;
  QR(17) QR(29) QR(16) QR(24)
  x0 += k2; x1 += k0 + 2u;
  QR(13) QR(15) QR(26) QR(6)
  x0 += k0; x1 += k1 + 3u;
  QR(17) QR(29) QR(16) QR(24)
  x0 += k1; x1 += k2 + 4u;
  QR(13) QR(15) QR(26) QR(6)
  x0 += k2; x1 += k0 + 5u;
#undef QR
  uint32_t bits = x0 ^ x1;
  const float lo = __uint_as_float(0xBF7FFFFFu);  // nextafter(-1,0)
  float f = __uint_as_float((bits >> 9) | 0x3F800000u) - 1.0f;
  float u = fmaxf(lo, __fadd_rn(__fmul_rn(f, 2.0f), lo));
  const float sqrt2 = 1.41421356237309515f;
  out[i] += (i < HALF_N ? std0 : std1) * (sqrt2 * erfinv_xla(u));
}

extern "C" void kernel_launch(void* const* d_in, const int* in_sizes, int n_in,
                              void* d_out, int out_size, void* d_ws, size_t ws_size,
                              hipStream_t stream) {
  const float* x = (const float*)d_in[0];
  float* ws = (float*)d_ws;
  float* Vt      = ws;
  float* partial = ws + 524288;
  float* out = (float*)d_out;

  stageB_kernel<<<512, 512, 0, stream>>>(x, Vt);
  stageC_kernel<<<512, 512, 0, stream>>>(Vt, out, partial);
  noise_kernel<<<2048, 256, 0, stream>>>(out, partial);
}

// Round 18
// 96.242 us; speedup vs baseline: 1.0223x; 1.0202x over previous
//
#include <hip/hip_runtime.h>
#include <stdint.h>
#include <math.h>

// PhysicsForwardModel: B=2, Nz=Nx=128, Ly=Lx=512.
// out[b,t,l] = (1/3) * sum_j Cy[j,l] * sum_k cos(F[k,j]*t) * a[k] * (Cy[:,:128] x[b] Cy[:,128:256]^T)[k,j]
//              + std_b * N(0,1)  (JAX threefry key=42, partitionable counters, XLA erfinv)
// R27 = R23 byte-for-byte (verified 97.16us, absmax 0.00195). R26's cooperative mega-kernel
//      failed correctness (grid.sync / cooperative launch unreliable under graph capture);
//      R24/R25's scheduling+TLP changes were null. This restores the best verified state.

#define HALF_N 262144  // 512*512 per-batch elements
#define PI_F 3.14159274101257324f

// ws layout (floats): Vt [0..524288) [j][b][t]; partial [524288..526336) 512 x {s0,q0,s1,q1}

__device__ __forceinline__ uint32_t rotl32(uint32_t v, int r) {
  return (v << r) | (v >> (32 - r));
}

// XLA ErfInv32 (Giles) -- matches reference's lax.erf_inv
__device__ __forceinline__ float erfinv_xla(float x) {
  float w = -log1pf(__fmul_rn(-x, x));
  float p;
  if (w < 5.0f) {
    w = w - 2.5f;
    p = 2.81022636e-08f;
    p = fmaf(p, w, 3.43273939e-07f);
    p = fmaf(p, w, -3.5233877e-06f);
    p = fmaf(p, w, -4.39150654e-06f);
    p = fmaf(p, w, 0.00021858087f);
    p = fmaf(p, w, -0.00125372503f);
    p = fmaf(p, w, -0.00417768164f);
    p = fmaf(p, w, 0.246640727f);
    p = fmaf(p, w, 1.50140941f);
  } else {
    w = __fsqrt_rn(w) - 3.0f;
    p = -0.000200214257f;
    p = fmaf(p, w, 0.000100950558f);
    p = fmaf(p, w, 0.00134934322f);
    p = fmaf(p, w, -0.00367342844f);
    p = fmaf(p, w, 0.00573950773f);
    p = fmaf(p, w, -0.0076224613f);
    p = fmaf(p, w, 0.00943887047f);
    p = fmaf(p, w, 1.00167406f);
    p = fmaf(p, w, 2.83297682f);
  }
  return p * x;
}

// Cy[k,n] = sc(k) * 2 * cos(pi*(2n+1)*k/1024), with n2p1 = (float)(2n+1) exact
__device__ __forceinline__ float cy_elem(float n2p1, float kf, float sc) {
  float t1 = __fmul_rn(PI_F, n2p1);
  float arg = __fmul_rn(t1, kf) * (1.0f / 1024.0f);
  return __fmul_rn(sc, __fmul_rn(2.0f, __cosf(arg)));
}

// fusedB, block = j (grid 512, 512 threads):
//   A  (tid<128): cyl[jj] = Cy[j,128+jj]
//   A2 (tid<256): us[b*128+i] = sum_jj x[b,i,jj]*cyl[jj]
//   B  (lane=k):  Chebyshev-recurred coefficients (anchors every 16 i, R1-exact exprs);
//                 kq[k] = {F[k,j], a*acc0, a*acc1, cos(32F)}
//   C  (kg=tid>>5, tg=tid&31): 16 t's {tg+32n}, k in [32kg,32kg+32):
//        anchors cos(F*tg), cos(F*(tg+32)) [ref-exact args], step 2*kq.w, recur 14.
__global__ __launch_bounds__(512, 4) void stageB_kernel(const float* __restrict__ x,
                                                        float* __restrict__ Vt) {
  __shared__ float cyl[128];
  __shared__ float us[256];
  __shared__ float4 kq[512];
  __shared__ float red[16][512];
  int j = blockIdx.x;
  int tid = threadIdx.x;
  float jf = (float)j;
  if (tid < 128) {
    float scj = (j == 0) ? (1.0f / __fsqrt_rn(2048.0f)) : 0.03125f;
    cyl[tid] = cy_elem((float)(2 * (128 + tid) + 1), jf, scj);
  }
  __syncthreads();
  if (tid < 256) {
    int b = tid >> 7, i = tid & 127;
    const float* xr = x + (b * 128 + i) * 128;
    float accA = 0.0f, accB = 0.0f;
    for (int jj = 0; jj < 128; jj += 8) {
      float4 xa = *(const float4*)&xr[jj];
      float4 xb = *(const float4*)&xr[jj + 4];
      float4 ca = *(const float4*)&cyl[jj];
      float4 cb = *(const float4*)&cyl[jj + 4];
      accA = fmaf(xa.x, ca.x, accA); accB = fmaf(xa.y, ca.y, accB);
      accA = fmaf(xa.z, ca.z, accA); accB = fmaf(xa.w, ca.w, accB);
      accA = fmaf(xb.x, cb.x, accA); accB = fmaf(xb.y, cb.y, accB);
      accA = fmaf(xb.z, cb.z, accA); accB = fmaf(xb.w, cb.w, accB);
    }
    us[tid] = accA + accB;
  }
  __syncthreads();
  {
    float kf = (float)tid;
    float sc = (tid == 0) ? (1.0f / __fsqrt_rn(2048.0f)) : 0.03125f;
    // coefficient recurrence step: 2*cos(pi*k/512)  (PI_F/512 exact pow2 scale)
    float thc = __cosf(__fmul_rn(kf, PI_F / 512.0f));
    float k2b = thc + thc;  // exact *2
    float a = cy_elem(1.0f, kf, sc);   // i=0 anchor (bit-identical)
    float c1 = cy_elem(3.0f, kf, sc);  // i=1 anchor (bit-identical)
    float acc0 = __fmul_rn(a, us[0]);
    float acc1 = __fmul_rn(a, us[128]);
    float accA0 = 0.f, accA1 = 0.f;
    acc0 = fmaf(c1, us[1], acc0);   acc1 = fmaf(c1, us[129], acc1);
    float cc2 = fmaf(k2b, c1, -a);      // i=2 (recurred)
    accA0 = fmaf(cc2, us[2], accA0); accA1 = fmaf(cc2, us[130], accA1);
    float cc3 = fmaf(k2b, cc2, -c1);    // i=3
    acc0 = fmaf(cc3, us[3], acc0);   acc1 = fmaf(cc3, us[131], acc1);
    float cm2 = cc2, cm1 = cc3;
#pragma unroll
    for (int q = 1; q < 4; ++q) {  // i = 4..15
      int i = q << 2;
      float4 v0 = *(const float4*)&us[i];
      float4 v1 = *(const float4*)&us[128 + i];
      float d0 = fmaf(k2b, cm1, -cm2);
      acc0 = fmaf(d0, v0.x, acc0);   acc1 = fmaf(d0, v1.x, acc1);
      float d1 = fmaf(k2b, d0, -cm1);
      accA0 = fmaf(d1, v0.y, accA0); accA1 = fmaf(d1, v1.y, accA1);
      float d2 = fmaf(k2b, d1, -d0);
      acc0 = fmaf(d2, v0.z, acc0);   acc1 = fmaf(d2, v1.z, acc1);
      float d3 = fmaf(k2b, d2, -d1);
      accA0 = fmaf(d3, v0.w, accA0); accA1 = fmaf(d3, v1.w, accA1);
      cm2 = d2; cm1 = d3;
    }
    for (int i0 = 16; i0 < 128; i0 += 16) {
      float b0f = (float)(2 * i0 + 1);
      float ca = cy_elem(b0f, kf, sc);                   // anchor i0 (R1-exact expr)
      float cb = cy_elem(__fadd_rn(b0f, 2.0f), kf, sc);  // anchor i0+1 (R1-exact expr)
      float4 u0 = *(const float4*)&us[i0];
      float4 u1 = *(const float4*)&us[128 + i0];
      acc0 = fmaf(ca, u0.x, acc0);   acc1 = fmaf(ca, u1.x, acc1);
      accA0 = fmaf(cb, u0.y, accA0); accA1 = fmaf(cb, u1.y, accA1);
      float d2 = fmaf(k2b, cb, -ca);
      acc0 = fmaf(d2, u0.z, acc0);   acc1 = fmaf(d2, u1.z, acc1);
      float d3 = fmaf(k2b, d2, -cb);
      accA0 = fmaf(d3, u0.w, accA0); accA1 = fmaf(d3, u1.w, accA1);
      cm2 = d2; cm1 = d3;
#pragma unroll
      for (int q = 1; q < 4; ++q) {
        int i = i0 + (q << 2);
        float4 v0 = *(const float4*)&us[i];
        float4 v1 = *(const float4*)&us[128 + i];
        float d0 = fmaf(k2b, cm1, -cm2);
        acc0 = fmaf(d0, v0.x, acc0);   acc1 = fmaf(d0, v1.x, acc1);
        float d1 = fmaf(k2b, d0, -cm1);
        accA0 = fmaf(d1, v0.y, accA0); accA1 = fmaf(d1, v1.y, accA1);
        float e2 = fmaf(k2b, d1, -d0);
        acc0 = fmaf(e2, v0.z, acc0);   acc1 = fmaf(e2, v1.z, acc1);
        float e3 = fmaf(k2b, e2, -d1);
        accA0 = fmaf(e3, v0.w, accA0); accA1 = fmaf(e3, v1.w, accA1);
        cm2 = e2; cm1 = e3;
      }
    }
    acc0 += accA0;
    acc1 += accA1;
    const float w0 = PI_F / 512.0f;  // exact pow2 scale of pi_f
    float ky = __fmul_rn(kf, w0);
    float kx = __fmul_rn(jf, w0);
    float fsv = __fsqrt_rn(__fadd_rn(__fmul_rn(ky, ky), __fmul_rn(kx, kx)));
    float cs = __cosf(__fmul_rn(fsv, 32.0f));  // t-step cosine, hoisted
    kq[tid] = make_float4(fsv, __fmul_rn(a, acc0), __fmul_rn(a, acc1), cs);
  }
  __syncthreads();
  // Phase C: thread (kg, tg); t = tg + 32n (n=0..15); k in [32kg, 32kg+32)
  int kg = tid >> 5, tg = tid & 31;
  int kbeg = kg << 5;
  float tfa = (float)tg;         // anchor t
  float tfb = (float)(tg + 32);  // anchor t + 32
  float a0[16], a1[16];
#pragma unroll
  for (int n = 0; n < 16; ++n) { a0[n] = 0.0f; a1[n] = 0.0f; }
  for (int kk = 0; kk < 32; ++kk) {
    float4 q = kq[kbeg + kk];
    float F = q.x, m0 = q.y, m1 = q.z;
    float k2 = q.w + q.w;  // 2*cos(32F), exact *2
    float ca = __cosf(__fmul_rn(F, tfa));  // bit-matches ref at t = tg
    float cb = __cosf(__fmul_rn(F, tfb));  // bit-matches ref at t = tg+32
    a0[0] = fmaf(ca, m0, a0[0]); a1[0] = fmaf(ca, m1, a1[0]);
    a0[1] = fmaf(cb, m0, a0[1]); a1[1] = fmaf(cb, m1, a1[1]);
#pragma unroll
    for (int n = 2; n < 16; ++n) {
      float cn = fmaf(k2, cb, -ca);
      a0[n] = fmaf(cn, m0, a0[n]); a1[n] = fmaf(cn, m1, a1[n]);
      ca = cb; cb = cn;
    }
  }
  // reduce b0 then b1 across kg (ascending, fixed order); red[kg][t] 2-way (free)
#pragma unroll
  for (int n = 0; n < 16; ++n) red[kg][(n << 5) + tg] = a0[n];
  __syncthreads();
  float s0 = red[0][tid];
#pragma unroll
  for (int g = 1; g < 16; ++g) s0 += red[g][tid];
  __syncthreads();
#pragma unroll
  for (int n = 0; n < 16; ++n) red[kg][(n << 5) + tg] = a1[n];
  __syncthreads();
  float s1 = red[0][tid];
#pragma unroll
  for (int g = 1; g < 16; ++g) s1 += red[g][tid];
  Vt[(j << 10) + tid] = s0;
  Vt[(j << 10) + 512 + tid] = s1;
}

// stageC v6: parity-symmetric (R21) + b128 j-pairs. block = t (grid 512, 256 threads).
__global__ __launch_bounds__(256, 4) void stageC_kernel(const float* __restrict__ Vt,
                                                        float* __restrict__ out,
                                                        float* __restrict__ partial) {
  __shared__ float vq[1024];  // [j][2] = {b0, b1} for this block's t
  int t = blockIdx.x;
  int tid = threadIdx.x;
  {
    const float* b0p = Vt + (tid << 10);
    const float* b1p = b0p + 512;
    vq[2 * tid] = b0p[t];
    vq[2 * tid + 1] = b1p[t];
    const float* b0q = Vt + ((tid + 256) << 10);
    const float* b1q = b0q + 512;
    vq[2 * tid + 512] = b0q[t];
    vq[2 * tid + 513] = b1q[t];
  }
  __syncthreads();
  int l = tid;
  float t1 = __fmul_rn(PI_F, (float)(2 * l + 1));
  float cth = __cosf(__fmul_rn(t1, 1.0f) * (1.0f / 1024.0f));
  float k2 = cth + cth;  // exact *2
  float cy0 = __fmul_rn(1.0f / __fsqrt_rn(2048.0f), 2.0f);
  float c16 = __fmul_rn(cy0, 16.0f);
  float e0, e1, o0, o1;
  float c_m1, c_m2;
  {
    // pair (0,1): b128 = {j0.b0, j0.b1, j1.b0, j1.b1}
    float4 v01 = *(const float4*)&vq[0];
    e0 = __fmul_rn(c16, v01.x);
    e1 = __fmul_rn(c16, v01.y);
    o0 = __fmul_rn(cth, v01.z);
    o1 = __fmul_rn(cth, v01.w);
    float c2v = __cosf(__fmul_rn(t1, 2.0f) * (1.0f / 1024.0f));
    // pair (2,3): c2 anchor, c3 recurred
    float4 v23 = *(const float4*)&vq[4];
    e0 = fmaf(c2v, v23.x, e0); e1 = fmaf(c2v, v23.y, e1);
    float c3 = fmaf(k2, c2v, -cth);
    o0 = fmaf(c3, v23.z, o0); o1 = fmaf(c3, v23.w, o1);
    c_m2 = c2v; c_m1 = c3;
#pragma unroll
    for (int j = 4; j < 16; j += 2) {
      float4 v = *(const float4*)&vq[j << 1];
      float cj = fmaf(k2, c_m1, -c_m2);
      e0 = fmaf(cj, v.x, e0); e1 = fmaf(cj, v.y, e1);
      float cj1 = fmaf(k2, cj, -c_m1);
      o0 = fmaf(cj1, v.z, o0); o1 = fmaf(cj1, v.w, o1);
      c_m2 = cj; c_m1 = cj1;
    }
  }
  for (int j0 = 16; j0 < 512; j0 += 16) {
    float jb = (float)j0;
    float ca = __cosf(__fmul_rn(t1, jb) * (1.0f / 1024.0f));                      // even
    float cb = __cosf(__fmul_rn(t1, __fadd_rn(jb, 1.0f)) * (1.0f / 1024.0f));    // odd
    float4 vab = *(const float4*)&vq[j0 << 1];
    e0 = fmaf(ca, vab.x, e0); e1 = fmaf(ca, vab.y, e1);
    o0 = fmaf(cb, vab.z, o0); o1 = fmaf(cb, vab.w, o1);
    c_m2 = ca; c_m1 = cb;
#pragma unroll
    for (int n = 2; n < 16; n += 2) {
      float4 v = *(const float4*)&vq[(j0 + n) << 1];
      float cj = fmaf(k2, c_m1, -c_m2);
      e0 = fmaf(cj, v.x, e0); e1 = fmaf(cj, v.y, e1);
      float cj1 = fmaf(k2, cj, -c_m1);
      o0 = fmaf(cj1, v.z, o0); o1 = fmaf(cj1, v.w, o1);
      c_m2 = cj; c_m1 = cj1;
    }
  }
  float pA0 = __fmul_rn(e0 + o0, 0.0625f) / 3.0f;  // (t, l, b0)
  float pA1 = __fmul_rn(e1 + o1, 0.0625f) / 3.0f;  // (t, l, b1)
  float pB0 = __fmul_rn(e0 - o0, 0.0625f) / 3.0f;  // (t, 511-l, b0)
  float pB1 = __fmul_rn(e1 - o1, 0.0625f) / 3.0f;  // (t, 511-l, b1)
  int lr = 511 - l;
  out[(t << 9) + l] = pA0;
  out[HALF_N + (t << 9) + l] = pA1;
  out[(t << 9) + lr] = pB0;
  out[HALF_N + (t << 9) + lr] = pB1;
  float s0 = pA0 + pB0, q0 = fmaf(pA0, pA0, pB0 * pB0);
  float s1 = pA1 + pB1, q1 = fmaf(pA1, pA1, pB1 * pB1);
  for (int off = 32; off > 0; off >>= 1) {
    s0 += __shfl_down(s0, off);
    q0 += __shfl_down(q0, off);
    s1 += __shfl_down(s1, off);
    q1 += __shfl_down(q1, off);
  }
  __shared__ float red[4][4];
  int wave = tid >> 6;
  if ((tid & 63) == 0) {
    red[wave][0] = s0; red[wave][1] = q0; red[wave][2] = s1; red[wave][3] = q1;
  }
  __syncthreads();
  if (tid == 0) {
    float a0 = 0.f, a1 = 0.f, a2 = 0.f, a3 = 0.f;
    for (int wv = 0; wv < 4; ++wv) {
      a0 += red[wv][0]; a1 += red[wv][1]; a2 += red[wv][2]; a3 += red[wv][3];
    }
    partial[blockIdx.x * 4 + 0] = a0;
    partial[blockIdx.x * 4 + 1] = a1;
    partial[blockIdx.x * 4 + 2] = a2;
    partial[blockIdx.x * 4 + 3] = a3;
  }
}

// Fused stats + noise: redundant partial reduce (512 quads) -> (std0,std1), then threefry noise.
// element i -> threefry2x32(key=(0,42), ctr=(0,i)), bits = o0^o1
__global__ __launch_bounds__(256) void noise_kernel(float* __restrict__ out,
                                                    const float* __restrict__ partial) {
  int tid = threadIdx.x;
  const float4* pq = (const float4*)partial;  // 512 quads {s0,q0,s1,q1}
  float4 pa = pq[tid];
  float4 pb = pq[tid + 256];
  float s0 = pa.x + pb.x, q0 = pa.y + pb.y, s1 = pa.z + pb.z, q1 = pa.w + pb.w;
  for (int off = 32; off > 0; off >>= 1) {
    s0 += __shfl_down(s0, off);
    q0 += __shfl_down(q0, off);
    s1 += __shfl_down(s1, off);
    q1 += __shfl_down(q1, off);
  }
  __shared__ float red[4][4];
  int wave = tid >> 6;
  if ((tid & 63) == 0) {
    red[wave][0] = s0; red[wave][1] = q0; red[wave][2] = s1; red[wave][3] = q1;
  }
  __syncthreads();
  float S = red[0][0] + red[1][0] + red[2][0] + red[3][0];
  float Q = red[0][1] + red[1][1] + red[2][1] + red[3][1];
  float S2 = red[0][2] + red[1][2] + red[2][2] + red[3][2];
  float Q2 = red[0][3] + red[1][3] + red[2][3] + red[3][3];
  const float invN = 1.0f / 262144.0f;
  float m0 = S * invN, m1 = S2 * invN;
  float std0 = __fsqrt_rn(fmaxf(Q * invN - m0 * m0, 0.0f));
  float std1 = __fsqrt_rn(fmaxf(Q2 * invN - m1 * m1, 0.0f));

  int i = blockIdx.x * 256 + tid;  // < 524288
  uint32_t x0 = 0u;
  uint32_t x1 = (uint32_t)i;
  const uint32_t k0 = 0u, k1 = 42u;
  const uint32_t k2 = k0 ^ k1 ^ 0x1BD11BDAu;
  x0 += k0; x1 += k1;
#define QR(r) x0 += x1; x1 = rotl32(x1, r); x1 ^= x0;
  QR(13) QR(15) QR(26) QR(6)
  x0 += k1; x1 += k2 + 1u;
  QR(17) QR(29) QR(16) QR(24)
  x0 += k2; x1 += k0 + 2u;
  QR(13) QR(15) QR(26) QR(6)
  x0 += k0; x1 += k1 + 3u;
  QR(17) QR(29) QR(16) QR(24)
  x0 += k1; x1 += k2 + 4u;
  QR(13) QR(15) QR(26) QR(6)
  x0 += k2; x1 += k0 + 5u;
#undef QR
  uint32_t bits = x0 ^ x1;
  const float lo = __uint_as_float(0xBF7FFFFFu);  // nextafter(-1,0)
  float f = __uint_as_float((bits >> 9) | 0x3F800000u) - 1.0f;
  float u = fmaxf(lo, __fadd_rn(__fmul_rn(f, 2.0f), lo));
  const float sqrt2 = 1.41421356237309515f;
  out[i] += (i < HALF_N ? std0 : std1) * (sqrt2 * erfinv_xla(u));
}

extern "C" void kernel_launch(void* const* d_in, const int* in_sizes, int n_in,
                              void* d_out, int out_size, void* d_ws, size_t ws_size,
                              hipStream_t stream) {
  const float* x = (const float*)d_in[0];
  float* ws = (float*)d_ws;
  float* Vt      = ws;
  float* partial = ws + 524288;
  float* out = (float*)d_out;

  stageB_kernel<<<512, 512, 0, stream>>>(x, Vt);
  stageC_kernel<<<512, 256, 0, stream>>>(Vt, out, partial);
  noise_kernel<<<2048, 256, 0, stream>>>(out, partial);
}